// Round 2
// baseline (35115.607 us; speedup 1.0000x reference)
//
#include <hip/hip_runtime.h>
#include <math.h>

#define B     512
#define SEQL  128
#define PT    5
#define EH    256
#define ZS    128
#define DH    512
#define NM    20
#define NMAXT 256

__device__ __forceinline__ float sigf(float x) { return 1.0f / (1.0f + expf(-x)); }

// ---------- generic transpose with zero-pad: out[c*rpad + r] = (r<rows)? in[r*cols + c] : 0
__global__ void transpose_pad(const float* __restrict__ in, float* __restrict__ out,
                              int rows, int cols, int rpad, long islice, long oslice)
{
    const float* ip = in + (size_t)blockIdx.z * islice;
    float* op = out + (size_t)blockIdx.z * oslice;
    int idx = blockIdx.x * 256 + threadIdx.x;
    if (idx >= cols * rpad) return;
    int c = idx / rpad, r = idx - c * rpad;
    op[idx] = (r < rows) ? ip[(size_t)r * cols + c] : 0.0f;
}

// ---------- encoder step: lane=batch, rows via scalar loads, no LDS, no barriers ----------
// grid (8 batch-groups, 32 hid-groups, 2 dirs), block 256 (4 waves; wave = 2 hid x 4 gates)
__global__ __launch_bounds__(256) void enc_step2(
    const float* __restrict__ sT,   // [SEQL][PT][B]
    const float* __restrict__ WihF, const float* __restrict__ WhhF, const float* __restrict__ bF,
    const float* __restrict__ WihB, const float* __restrict__ WhhB, const float* __restrict__ bB,
    const float* __restrict__ hfin, float* __restrict__ hfout, float* __restrict__ cf,
    const float* __restrict__ hbin, float* __restrict__ hbout, float* __restrict__ cb,
    int t)
{
    const int dir = blockIdx.z;
    const float* Wih  = dir ? WihB : WihF;
    const float* Whh  = dir ? WhhB : WhhF;
    const float* bias = dir ? bB   : bF;
    const float* hin  = dir ? hbin : hfin;
    float* hout       = dir ? hbout: hfout;
    float* c          = dir ? cb   : cf;
    const int ts = dir ? (SEQL - 1 - t) : t;

    const int lane = threadIdx.x & 63;
    const int wv   = __builtin_amdgcn_readfirstlane(threadIdx.x >> 6);
    const int b    = blockIdx.x * 64 + lane;
    const int n0   = blockIdx.y * 8 + wv * 2;

    float acc[2][4] = {};
    #pragma unroll 4
    for (int k0 = 0; k0 < EH; k0 += 4) {
        const float a0 = hin[(size_t)(k0 + 0) * B + b];
        const float a1 = hin[(size_t)(k0 + 1) * B + b];
        const float a2 = hin[(size_t)(k0 + 2) * B + b];
        const float a3 = hin[(size_t)(k0 + 3) * B + b];
        #pragma unroll
        for (int j = 0; j < 2; ++j)
        #pragma unroll
        for (int g = 0; g < 4; ++g) {
            const float4 w = *(const float4*)&Whh[((size_t)(g * EH + n0 + j)) * EH + k0];
            float v = acc[j][g];
            v = fmaf(a0, w.x, v); v = fmaf(a1, w.y, v);
            v = fmaf(a2, w.z, v); v = fmaf(a3, w.w, v);
            acc[j][g] = v;
        }
    }

    float xv[PT];
    #pragma unroll
    for (int p = 0; p < PT; ++p) xv[p] = sT[((size_t)ts * PT + p) * B + b];

    #pragma unroll
    for (int j = 0; j < 2; ++j) {
        const int n = n0 + j;
        float gv[4];
        #pragma unroll
        for (int g = 0; g < 4; ++g) {
            const int row = g * EH + n;
            float v = acc[j][g] + bias[row];
            const float* wr = Wih + (size_t)row * PT;
            #pragma unroll
            for (int p = 0; p < PT; ++p) v = fmaf(xv[p], wr[p], v);
            gv[g] = v;
        }
        const size_t idx = (size_t)n * B + b;
        const float cv = sigf(gv[1]) * c[idx] + sigf(gv[0]) * tanhf(gv[2]);
        c[idx] = cv;
        hout[idx] = sigf(gv[3]) * tanhf(cv);
    }
}

// ---------- latent: mu/sigma + reparam; lane=batch ----------
// grid (8, 16), block 256
__global__ __launch_bounds__(256) void latent2(
    const float* __restrict__ hfT, const float* __restrict__ hbT,
    const float* __restrict__ Wmu, const float* __restrict__ bmu,
    const float* __restrict__ Wsig, const float* __restrict__ bsig,
    const float* __restrict__ zepsT, float* __restrict__ zT)
{
    const int lane = threadIdx.x & 63;
    const int wv   = __builtin_amdgcn_readfirstlane(threadIdx.x >> 6);
    const int b    = blockIdx.x * 64 + lane;
    const int n0   = blockIdx.y * 8 + wv * 2;

    float am[2] = {}, as2[2] = {};
    #pragma unroll 4
    for (int k0 = 0; k0 < 2 * EH; k0 += 4) {
        const float* hsrc = (k0 < EH) ? hfT : hbT;
        const int kk = k0 & (EH - 1);
        const float a0 = hsrc[(size_t)(kk + 0) * B + b];
        const float a1 = hsrc[(size_t)(kk + 1) * B + b];
        const float a2 = hsrc[(size_t)(kk + 2) * B + b];
        const float a3 = hsrc[(size_t)(kk + 3) * B + b];
        #pragma unroll
        for (int j = 0; j < 2; ++j) {
            const float4 wm = *(const float4*)&Wmu[((size_t)(n0 + j)) * (2 * EH) + k0];
            const float4 ws = *(const float4*)&Wsig[((size_t)(n0 + j)) * (2 * EH) + k0];
            float u = am[j], v = as2[j];
            u = fmaf(a0, wm.x, u); u = fmaf(a1, wm.y, u); u = fmaf(a2, wm.z, u); u = fmaf(a3, wm.w, u);
            v = fmaf(a0, ws.x, v); v = fmaf(a1, ws.y, v); v = fmaf(a2, ws.z, v); v = fmaf(a3, ws.w, v);
            am[j] = u; as2[j] = v;
        }
    }
    #pragma unroll
    for (int j = 0; j < 2; ++j) {
        const int n = n0 + j;
        const float mu = am[j] + bmu[n];
        const float sg = expf(0.5f * (as2[j] + bsig[n]));
        zT[(size_t)n * B + b] = fmaf(sg, zepsT[(size_t)n * B + b], mu);
    }
}

// ---------- h0 = tanh(z @ Wh0^T + bh0), transposed out; grid (8,16) ----------
__global__ __launch_bounds__(256) void h02(
    const float* __restrict__ zT, const float* __restrict__ Wh0,
    const float* __restrict__ bh0, float* __restrict__ hcT)
{
    const int lane = threadIdx.x & 63;
    const int wv   = __builtin_amdgcn_readfirstlane(threadIdx.x >> 6);
    const int b    = blockIdx.x * 64 + lane;
    const int n0   = blockIdx.y * 32 + wv * 8;

    float acc[8] = {};
    #pragma unroll 2
    for (int k0 = 0; k0 < ZS; k0 += 4) {
        const float a0 = zT[(size_t)(k0 + 0) * B + b];
        const float a1 = zT[(size_t)(k0 + 1) * B + b];
        const float a2 = zT[(size_t)(k0 + 2) * B + b];
        const float a3 = zT[(size_t)(k0 + 3) * B + b];
        #pragma unroll
        for (int r = 0; r < 8; ++r) {
            const float4 w = *(const float4*)&Wh0[((size_t)(n0 + r)) * ZS + k0];
            float v = acc[r];
            v = fmaf(a0, w.x, v); v = fmaf(a1, w.y, v);
            v = fmaf(a2, w.z, v); v = fmaf(a3, w.w, v);
            acc[r] = v;
        }
    }
    #pragma unroll
    for (int r = 0; r < 8; ++r)
        hcT[(size_t)(n0 + r) * B + b] = tanhf(acc[r] + bh0[n0 + r]);
}

// ---------- CzT = (z @ Wih[:,5:133]^T + decB)^T ; grid (8,64) ----------
__global__ __launch_bounds__(256) void cz2(
    const float* __restrict__ zT, const float* __restrict__ Wih,
    const float* __restrict__ bias, float* __restrict__ CzT)
{
    const int lane = threadIdx.x & 63;
    const int wv   = __builtin_amdgcn_readfirstlane(threadIdx.x >> 6);
    const int b    = blockIdx.x * 64 + lane;
    const int r0   = blockIdx.y * 32 + wv * 8;

    float acc[8] = {};
    #pragma unroll 4
    for (int k = 0; k < ZS; ++k) {
        const float a = zT[(size_t)k * B + b];
        #pragma unroll
        for (int r = 0; r < 8; ++r)
            acc[r] = fmaf(a, Wih[(size_t)(r0 + r) * 133 + 5 + k], acc[r]);
    }
    #pragma unroll
    for (int r = 0; r < 8; ++r)
        CzT[(size_t)(r0 + r) * B + b] = acc[r] + bias[r0 + r];
}

// ---------- decoder LSTM step: lane=batch, scalar-pipe weights, fused pointwise ----------
// grid (8 batch-groups, 64 hid-groups), block 256
__global__ __launch_bounds__(256) void dec_step2(
    const float* __restrict__ hin, float* __restrict__ hout, float* __restrict__ cT,
    const float* __restrict__ CzT, const float* __restrict__ Whh,
    const float* __restrict__ Wih, const float* __restrict__ prevPt, int t)
{
    const int lane = threadIdx.x & 63;
    const int wv   = __builtin_amdgcn_readfirstlane(threadIdx.x >> 6);
    const int b    = blockIdx.x * 64 + lane;
    const int n0   = blockIdx.y * 8 + wv * 2;

    float acc[2][4] = {};
    #pragma unroll 4
    for (int k0 = 0; k0 < DH; k0 += 4) {
        const float a0 = hin[(size_t)(k0 + 0) * B + b];
        const float a1 = hin[(size_t)(k0 + 1) * B + b];
        const float a2 = hin[(size_t)(k0 + 2) * B + b];
        const float a3 = hin[(size_t)(k0 + 3) * B + b];
        #pragma unroll
        for (int j = 0; j < 2; ++j)
        #pragma unroll
        for (int g = 0; g < 4; ++g) {
            const float4 w = *(const float4*)&Whh[((size_t)(g * DH + n0 + j)) * DH + k0];
            float v = acc[j][g];
            v = fmaf(a0, w.x, v); v = fmaf(a1, w.y, v);
            v = fmaf(a2, w.z, v); v = fmaf(a3, w.w, v);
            acc[j][g] = v;
        }
    }

    float pv0, pv1, pv2, pv3, pv4;
    if (t == 0) { pv0 = 0.f; pv1 = 0.f; pv2 = 1.f; pv3 = 0.f; pv4 = 0.f; }
    else {
        const float* pp = prevPt + (size_t)b * 5;
        pv0 = pp[0]; pv1 = pp[1]; pv2 = pp[2]; pv3 = pp[3]; pv4 = pp[4];
    }

    #pragma unroll
    for (int j = 0; j < 2; ++j) {
        const int n = n0 + j;
        float gv[4];
        #pragma unroll
        for (int g = 0; g < 4; ++g) {
            const size_t row = (size_t)(g * DH + n);
            float v = acc[j][g] + CzT[row * B + b];
            const float* wr = Wih + row * 133;
            v = fmaf(pv0, wr[0], v); v = fmaf(pv1, wr[1], v); v = fmaf(pv2, wr[2], v);
            v = fmaf(pv3, wr[3], v); v = fmaf(pv4, wr[4], v);
            gv[g] = v;
        }
        const size_t idx = (size_t)n * B + b;
        const float cv = sigf(gv[1]) * cT[idx] + sigf(gv[0]) * tanhf(gv[2]);
        cT[idx] = cv;
        hout[idx] = sigf(gv[3]) * tanhf(cv);
    }
}

// ---------- Y = h @ Wdec^T + bdec fused with GMM sampler ----------
// grid 64 blocks x 128 threads; block = 8 batches x 128 cols (123 used)
__global__ __launch_bounds__(128) void ysamp(
    const float* __restrict__ hT, const float* __restrict__ WdecT,  // [512][128], zero-padded
    const float* __restrict__ bdec,
    const float* __restrict__ geps, const float* __restrict__ penu,
    float* __restrict__ out, int t)
{
    const int col = threadIdx.x & 127;
    const int b0  = blockIdx.x * 8;

    float acc[8] = {};
    #pragma unroll 4
    for (int k = 0; k < DH; ++k) {
        const float w  = WdecT[(size_t)k * 128 + col];
        const float4 aL = *(const float4*)&hT[(size_t)k * B + b0];
        const float4 aH = *(const float4*)&hT[(size_t)k * B + b0 + 4];
        acc[0] = fmaf(aL.x, w, acc[0]); acc[1] = fmaf(aL.y, w, acc[1]);
        acc[2] = fmaf(aL.z, w, acc[2]); acc[3] = fmaf(aL.w, w, acc[3]);
        acc[4] = fmaf(aH.x, w, acc[4]); acc[5] = fmaf(aH.y, w, acc[5]);
        acc[6] = fmaf(aH.z, w, acc[6]); acc[7] = fmaf(aH.w, w, acc[7]);
    }

    __shared__ float Y[8][128];
    const float bd = (col < 123) ? bdec[col] : 0.0f;
    #pragma unroll
    for (int j = 0; j < 8; ++j) Y[j][col] = acc[j] + bd;
    __syncthreads();

    if (threadIdx.x < 8) {
        const int b = b0 + threadIdx.x;
        const float* y = Y[threadIdx.x];

        float mmax = y[0];
        #pragma unroll
        for (int m = 1; m < NM; ++m) mmax = fmaxf(mmax, y[6 * m]);
        float pe[NM];
        float psum = 0.f;
        #pragma unroll
        for (int m = 0; m < NM; ++m) { pe[m] = expf(y[6 * m] - mmax); psum += pe[m]; }

        const float* ep = geps + ((size_t)t * B + b) * NM * 2;
        float dx = 0.f, dy = 0.f;
        #pragma unroll
        for (int m = 0; m < NM; ++m) {
            const float pim = pe[m] / psum;
            const float mx = y[6 * m + 1], my = y[6 * m + 2];
            const float sx = expf(y[6 * m + 3]), sy = expf(y[6 * m + 4]);
            const float cor = tanhf(y[6 * m + 5]);
            const float l21 = cor / sx;
            const float l22 = sqrtf(fmaxf(sy * sy - l21 * l21, 1e-6f));
            const float e1 = ep[2 * m], e2 = ep[2 * m + 1];
            dx += pim * (mx + sx * e1);
            dy += pim * (my + fmaf(l21, e1, l22 * e2));
        }

        const float q0 = y[120], q1 = y[121], q2 = y[122];
        const float qm = fmaxf(q0, fmaxf(q1, q2));
        const float e0 = expf(q0 - qm), e1q = expf(q1 - qm), e2q = expf(q2 - qm);
        const float qs = e0 + e1q + e2q;

        const float* u = penu + ((size_t)t * B + b) * 3;
        float* o = out + ((size_t)t * B + b) * 5;
        o[0] = dx;
        o[1] = dy;
        o[2] = (u[0] < e0  / qs) ? 1.f : 0.f;
        o[3] = (u[1] < e1q / qs) ? 1.f : 0.f;
        o[4] = (u[2] < e2q / qs) ? 1.f : 0.f;
    }
}

extern "C" void kernel_launch(void* const* d_in, const int* in_sizes, int n_in,
                              void* d_out, int out_size, void* d_ws, size_t ws_size,
                              hipStream_t stream)
{
    (void)in_sizes; (void)n_in; (void)out_size; (void)ws_size;

    const float* s      = (const float*)d_in[0];
    const float* WihF   = (const float*)d_in[1];
    const float* WhhF   = (const float*)d_in[2];
    const float* bF     = (const float*)d_in[3];
    const float* WihB   = (const float*)d_in[4];
    const float* WhhB   = (const float*)d_in[5];
    const float* bB     = (const float*)d_in[6];
    const float* Wmu    = (const float*)d_in[7];
    const float* bmu    = (const float*)d_in[8];
    const float* Wsig   = (const float*)d_in[9];
    const float* bsig   = (const float*)d_in[10];
    const float* Wh0    = (const float*)d_in[11];
    const float* bh0    = (const float*)d_in[12];
    const float* decWih = (const float*)d_in[13];
    const float* decWhh = (const float*)d_in[14];
    const float* decB   = (const float*)d_in[15];
    const float* Wdec   = (const float*)d_in[16];
    const float* bdec   = (const float*)d_in[17];
    const float* zeps   = (const float*)d_in[18];
    const float* geps   = (const float*)d_in[19];
    const float* penu   = (const float*)d_in[20];

    float* out = (float*)d_out;
    float* p   = (float*)d_ws;

    float* hfA  = p; p += 131072;   // enc fwd h (transposed [256][512])
    float* hbA  = p; p += 131072;
    float* cf   = p; p += 131072;
    float* cb   = p; p += 131072;
    float* cdT  = p; p += 262144;   // dec c [512][512]
    float* hfB  = p; p += 131072;
    float* hbB  = p; p += 131072;
    float* hA   = p; p += 262144;   // dec h ping-pong [512][512]
    float* hB   = p; p += 262144;
    float* zT   = p; p += 65536;    // [128][512]
    float* CzT  = p; p += 1048576;  // [2048][512]
    float* sT   = p; p += 327680;   // [128][5][512]
    float* zepsT= p; p += 65536;    // [128][512]
    float* WdecT= p; p += 65536;    // [512][128]

    // zero hfA, hbA, cf, cb, cdT (contiguous)
    hipMemsetAsync((void*)hfA, 0, (size_t)(4 * 131072 + 262144) * sizeof(float), stream);

    // transposes: sT (128 slices of [512][5] -> [5][512]), zepsT, WdecT (pad cols>=123 -> 0)
    transpose_pad<<<dim3(10, 1, SEQL), 256, 0, stream>>>(s, sT, B, PT, B, (long)B * PT, (long)B * PT);
    transpose_pad<<<dim3(256, 1, 1), 256, 0, stream>>>(zeps, zepsT, B, ZS, B, 0, 0);
    transpose_pad<<<dim3(256, 1, 1), 256, 0, stream>>>(Wdec, WdecT, 123, DH, 128, 0, 0);

    for (int t = 0; t < SEQL; ++t) {
        const float* hfin = (t & 1) ? hfB : hfA;  float* hfout = (t & 1) ? hfA : hfB;
        const float* hbin = (t & 1) ? hbB : hbA;  float* hbout = (t & 1) ? hbA : hbB;
        enc_step2<<<dim3(8, 32, 2), 256, 0, stream>>>(
            sT, WihF, WhhF, bF, WihB, WhhB, bB,
            hfin, hfout, cf, hbin, hbout, cb, t);
    }
    // t=127 (odd) wrote the A buffers
    latent2<<<dim3(8, 16), 256, 0, stream>>>(hfA, hbA, Wmu, bmu, Wsig, bsig, zepsT, zT);
    h02<<<dim3(8, 16), 256, 0, stream>>>(zT, Wh0, bh0, hA);
    cz2<<<dim3(8, 64), 256, 0, stream>>>(zT, decWih, decB, CzT);

    for (int t = 0; t < NMAXT; ++t) {
        const float* hin = (t & 1) ? hB : hA;
        float* hout      = (t & 1) ? hA : hB;
        dec_step2<<<dim3(8, 64), 256, 0, stream>>>(
            hin, hout, cdT, CzT, decWhh, decWih,
            t ? (out + (size_t)(t - 1) * B * 5) : out, t);
        ysamp<<<dim3(64), 128, 0, stream>>>(hout, WdecT, bdec, geps, penu, out, t);
    }
}